// Round 1
// baseline (580.266 us; speedup 1.0000x reference)
//
#include <hip/hip_runtime.h>

// Problem constants
constexpr int Dd  = 256;       // embedding dim (= C)
constexpr int Kk  = 1024;      // codebook entries
constexpr int Nn  = 65536;     // B*H*W points
constexpr long long QOFF     = 1;          // quantized starts at d_out[1]
constexpr long long PERP_OFF = 16777217LL; // 1 + 16777216
constexpr long long ENC_OFF  = 16777218LL; // start of encodings
constexpr long long ENC_CNT  = 67108864LL; // N*K

// ws layout (bytes):
//   [0,     4096)  int   counts[1024]      (memset 0 each call)
//   [4096,  8192)  float enorm[1024]
//   [8192, 12288)  float partials[1024]
//   [16384, +256K) int   idx[65536]

// ---------------- K0: codebook row squared norms ----------------
__global__ void enorm_kernel(const float* __restrict__ emb, float* __restrict__ enorm) {
    int k = blockIdx.x * 256 + threadIdx.x;
    const float4* r = reinterpret_cast<const float4*>(emb + (size_t)k * Dd);
    float a = 0.f;
#pragma unroll 8
    for (int i = 0; i < Dd / 4; ++i) {
        float4 v = r[i];
        a = fmaf(v.x, v.x, a); a = fmaf(v.y, v.y, a);
        a = fmaf(v.z, v.z, a); a = fmaf(v.w, v.w, a);
    }
    enorm[k] = a;
}

// ---------------- K1: argmin over codebook (fp32 GEMM-like) ----------------
// Block: 512 threads (8 waves). Tile: 128 points x 256 codes per k-pass (4 passes).
// Micro-tile per thread: 8 points x 8 codes. D staged in chunks of 32.
// score = ||e||^2 - 2*dot  (||x||^2 constant per point, dropped)
__global__ __launch_bounds__(512) void argmin_kernel(
    const float* __restrict__ in,      // [B][C][H*W] = [64][256][1024]
    const float* __restrict__ emb,     // [1024][256]
    const float* __restrict__ enorm,   // [1024]
    int* __restrict__ idx_out)         // [65536]
{
    __shared__ float xs[32][132];  // [d][point], pad 128->132 (16B-aligned rows)
    __shared__ float es[32][260];  // [d][code],  pad 256->260

    const int t  = threadIdx.x;
    const int tx = t & 31;     // code group (8 codes each)
    const int ty = t >> 5;     // point group 0..15 (8 points each)
    const int n0 = blockIdx.x * 128;
    const int b   = n0 >> 10;
    const int hw0 = n0 & 1023;
    const float* inb = in + (size_t)b * Dd * 1024;

    float bd[8];
    int   bi[8];
#pragma unroll
    for (int i = 0; i < 8; ++i) { bd[i] = 3.4e38f; bi[i] = 0; }

    for (int kp = 0; kp < 4; ++kp) {
        float acc[8][8];
#pragma unroll
        for (int i = 0; i < 8; ++i)
#pragma unroll
            for (int j = 0; j < 8; ++j) acc[i][j] = 0.f;

        for (int dc = 0; dc < Dd; dc += 32) {
            __syncthreads();
            // stage x: 32 d x 128 hw  (no transpose needed: contiguous along hw)
            {
                const int wi = (t & 31) << 2;  // 0..124
                const int di = t >> 5;         // 0..15
#pragma unroll
                for (int r = 0; r < 2; ++r) {
                    int d = di + 16 * r;
                    float4 v = *reinterpret_cast<const float4*>(
                        inb + (size_t)(dc + d) * 1024 + hw0 + wi);
                    *reinterpret_cast<float4*>(&xs[d][wi]) = v;
                }
            }
            // stage e transposed: es[d][k] from emb[k][d]
            {
                const int kk   = t & 31;
                const int rest = t >> 5;      // 0..15
                const int dj   = rest & 7;    // d sub-group (4 floats)
                const int kh   = rest >> 3;   // 0..1
#pragma unroll
                for (int r = 0; r < 4; ++r) {
                    int kl = kk + 32 * kh + 64 * r;      // 0..255
                    int kg = kp * 256 + kl;
                    int dd = 4 * dj;
                    float4 v = *reinterpret_cast<const float4*>(
                        emb + (size_t)kg * Dd + dc + dd);
                    es[dd + 0][kl] = v.x;
                    es[dd + 1][kl] = v.y;
                    es[dd + 2][kl] = v.z;
                    es[dd + 3][kl] = v.w;
                }
            }
            __syncthreads();

#pragma unroll 4
            for (int d = 0; d < 32; ++d) {
                float4 xa = *reinterpret_cast<const float4*>(&xs[d][8 * ty]);
                float4 xb = *reinterpret_cast<const float4*>(&xs[d][8 * ty + 4]);
                float4 ea = *reinterpret_cast<const float4*>(&es[d][8 * tx]);
                float4 eb = *reinterpret_cast<const float4*>(&es[d][8 * tx + 4]);
                float xr[8] = {xa.x, xa.y, xa.z, xa.w, xb.x, xb.y, xb.z, xb.w};
                float er[8] = {ea.x, ea.y, ea.z, ea.w, eb.x, eb.y, eb.z, eb.w};
#pragma unroll
                for (int i = 0; i < 8; ++i)
#pragma unroll
                    for (int j = 0; j < 8; ++j)
                        acc[i][j] = fmaf(xr[i], er[j], acc[i][j]);
            }
        }

        // epilogue: fold this k-chunk into running argmin
#pragma unroll
        for (int j = 0; j < 8; ++j) {
            int kg = kp * 256 + 8 * tx + j;
            float en = enorm[kg];
#pragma unroll
            for (int i = 0; i < 8; ++i) {
                float s = en - 2.0f * acc[i][j];
                if (s < bd[i]) { bd[i] = s; bi[i] = kg; }
            }
        }
    }

    // reduce across the 32 tx-threads (half-wave); prefer lower idx on ties
#pragma unroll
    for (int i = 0; i < 8; ++i) {
#pragma unroll
        for (int m = 1; m < 32; m <<= 1) {
            float od = __shfl_xor(bd[i], m);
            int   oi = __shfl_xor(bi[i], m);
            if (od < bd[i] || (od == bd[i] && oi < bi[i])) { bd[i] = od; bi[i] = oi; }
        }
    }
    if (tx == 0) {
#pragma unroll
        for (int i = 0; i < 8; ++i) idx_out[n0 + ty * 8 + i] = bi[i];
    }
}

// ---------------- K2: quantized output + loss partials + counts ----------------
// Block: 256 threads = 64 points x 4 c-quarters. Each thread streams one codebook
// row (L1-resident lines) and writes out coalesced along hw.
__global__ __launch_bounds__(256) void quant_kernel(
    const float* __restrict__ in, const float* __restrict__ emb,
    const int* __restrict__ idx, float* __restrict__ outq,
    float* __restrict__ partials, int* __restrict__ counts)
{
    __shared__ float sred[4];
    const int t  = threadIdx.x;
    const int p  = t & 63;
    const int cq = t >> 6;
    const int n0 = blockIdx.x * 64;
    const int b   = n0 >> 10;
    const int hw0 = n0 & 1023;
    const int row = idx[n0 + p];
    if (t < 64) atomicAdd(&counts[row], 1);

    const float* erow = emb + (size_t)row * Dd;
    const size_t base = (size_t)b * Dd * 1024 + hw0 + p;
    float ls = 0.f;
    for (int c0 = cq * 64; c0 < cq * 64 + 64; c0 += 4) {
        float4 ev = *reinterpret_cast<const float4*>(erow + c0);
        float e4[4] = {ev.x, ev.y, ev.z, ev.w};
#pragma unroll
        for (int j = 0; j < 4; ++j) {
            size_t a = base + (size_t)(c0 + j) * 1024;
            float q = e4[j];
            float x = in[a];
            outq[a] = q;
            float df = q - x;
            ls = fmaf(df, df, ls);
        }
    }
    // deterministic block reduction
#pragma unroll
    for (int m = 1; m < 64; m <<= 1) ls += __shfl_xor(ls, m);
    if ((t & 63) == 0) sred[t >> 6] = ls;
    __syncthreads();
    if (t == 0) partials[blockIdx.x] = (sred[0] + sred[1]) + (sred[2] + sred[3]);
}

// ---------------- K3: one-hot encodings (256 MB fill) ----------------
// enc = d_out + ENC_OFF is 8 mod 16 aligned: 2 scalar head/tail, float4 body.
__global__ void enc_kernel(const int* __restrict__ idx, float* __restrict__ enc) {
    const long long T = 16777215LL;  // float4 chunks in body
    long long gid    = (long long)blockIdx.x * 256 + threadIdx.x;
    long long stride = (long long)gridDim.x * 256;
    if (gid == 0) {
        enc[0] = (idx[0] == 0) ? 1.f : 0.f;
        enc[1] = (idx[0] == 1) ? 1.f : 0.f;
        enc[67108862LL] = (idx[65535] == 1022) ? 1.f : 0.f;
        enc[67108863LL] = (idx[65535] == 1023) ? 1.f : 0.f;
    }
    for (long long c = gid; c < T; c += stride) {
        long long rel = 2 + 4 * c;
        int n  = (int)(rel >> 10);
        int kk = (int)(rel & 1023);
        float4 v;
        if (kk <= 1020) {
            int iv = idx[n];
            v.x = (kk     == iv) ? 1.f : 0.f;
            v.y = (kk + 1 == iv) ? 1.f : 0.f;
            v.z = (kk + 2 == iv) ? 1.f : 0.f;
            v.w = (kk + 3 == iv) ? 1.f : 0.f;
        } else {
            float o[4];
#pragma unroll
            for (int j = 0; j < 4; ++j) {
                long long rr = rel + j;
                int nn = (int)(rr >> 10);
                int kj = (int)(rr & 1023);
                o[j] = (idx[nn] == kj) ? 1.f : 0.f;
            }
            v.x = o[0]; v.y = o[1]; v.z = o[2]; v.w = o[3];
        }
        *reinterpret_cast<float4*>(enc + rel) = v;
    }
}

// ---------------- K4: finalize loss + perplexity ----------------
__global__ __launch_bounds__(1024) void fin_kernel(
    const int* __restrict__ counts, const float* __restrict__ partials,
    float* __restrict__ out)
{
    __shared__ float r1[16];
    __shared__ float r2[16];
    const int t = threadIdx.x;
    float pl = partials[t];
    float pv = (float)counts[t] * (1.0f / 65536.0f);
    float pp = pv * logf(pv + 1e-10f);
#pragma unroll
    for (int m = 1; m < 64; m <<= 1) {
        pl += __shfl_xor(pl, m);
        pp += __shfl_xor(pp, m);
    }
    if ((t & 63) == 0) { r1[t >> 6] = pl; r2[t >> 6] = pp; }
    __syncthreads();
    if (t == 0) {
        float s1 = 0.f, s2 = 0.f;
#pragma unroll
        for (int i = 0; i < 16; ++i) { s1 += r1[i]; s2 += r2[i]; }
        out[0]        = 0.25f * s1 / 16777216.0f;   // commitment loss
        out[PERP_OFF] = expf(-s2);                  // perplexity
    }
}

extern "C" void kernel_launch(void* const* d_in, const int* in_sizes, int n_in,
                              void* d_out, int out_size, void* d_ws, size_t ws_size,
                              hipStream_t stream) {
    const float* in  = (const float*)d_in[0];
    const float* emb = (const float*)d_in[1];
    float* out = (float*)d_out;

    char* ws = (char*)d_ws;
    int*   counts   = (int*)ws;                // 4 KB
    float* enorm    = (float*)(ws + 4096);     // 4 KB
    float* partials = (float*)(ws + 8192);     // 4 KB
    int*   idx      = (int*)(ws + 16384);      // 256 KB

    hipMemsetAsync(counts, 0, 4096, stream);
    enorm_kernel<<<4, 256, 0, stream>>>(emb, enorm);
    argmin_kernel<<<512, 512, 0, stream>>>(in, emb, enorm, idx);
    quant_kernel<<<1024, 256, 0, stream>>>(in, emb, idx, out + QOFF, partials, counts);
    enc_kernel<<<8192, 256, 0, stream>>>(idx, out + ENC_OFF);
    fin_kernel<<<1, 1024, 0, stream>>>(counts, partials, out);
}

// Round 3
// 426.105 us; speedup vs baseline: 1.3618x; 1.3618x over previous
//
#include <hip/hip_runtime.h>

typedef _Float16 f16;
typedef _Float16 f16x4 __attribute__((ext_vector_type(4)));
typedef _Float16 f16x8 __attribute__((ext_vector_type(8)));
typedef float f32x4 __attribute__((ext_vector_type(4)));

constexpr int Dd = 256;
constexpr long long QOFF     = 1;
constexpr long long PERP_OFF = 16777217LL;
constexpr long long ENC_OFF  = 16777218LL;
constexpr long long ENC_CNT  = 67108864LL;

// ---------------- K0: split codebook to fp16 hi/lo + exact row norms ----------------
__global__ void prep_kernel(const float* __restrict__ emb, f16* __restrict__ ehs,
                            f16* __restrict__ els, float* __restrict__ enorm) {
    const int t = threadIdx.x;
    const int k = blockIdx.x * 4 + (t >> 6);
    const int d4 = (t & 63) * 4;
    float4 v = *reinterpret_cast<const float4*>(emb + (size_t)k * Dd + d4);
    float s = v.x * v.x + v.y * v.y + v.z * v.z + v.w * v.w;
#pragma unroll
    for (int m = 1; m < 64; m <<= 1) s += __shfl_xor(s, m);
    float a[4] = {v.x, v.y, v.z, v.w};
    f16x4 h, l;
#pragma unroll
    for (int j = 0; j < 4; ++j) {
        h[j] = (f16)a[j];
        l[j] = (f16)(a[j] - (float)h[j]);
    }
    *reinterpret_cast<f16x4*>(ehs + (size_t)k * Dd + d4) = h;
    *reinterpret_cast<f16x4*>(els + (size_t)k * Dd + d4) = l;
    if ((t & 63) == 0) enorm[k] = s;
}

// ---------------- K1: MFMA top-2 argmin ----------------
// Block 256 thr = 4 waves, 64 points. x staged [p][d] fp16 hi/lo in LDS, XOR-swizzled.
// Wave w handles codes [w*256, w*256+256), two 16-code chunks per x-fragment load.
// approx score = ||e||^2 - 2*(eh.xh + el.xh + eh.xl); exact refine fixes near-ties.
__global__ __launch_bounds__(256, 2) void argmin_kernel(
    const float* __restrict__ in, const f16* __restrict__ ehs,
    const f16* __restrict__ els, const float* __restrict__ enorm,
    int* __restrict__ i2a, int* __restrict__ i2b)
{
    __shared__ char lds[65536];   // [0,32K): xh[64][256], [32K,64K): xl — swizzled
    const int t  = threadIdx.x;
    const int n0 = blockIdx.x * 64;
    const int b = n0 >> 10, hw0 = n0 & 1023;
    const float* inb = in + (size_t)b * (Dd * 1024) + hw0;

    // ---- stage x: transpose + fp16 split; byte_off = (p*512 + d*2) ^ ((p&15)<<4) ----
    {
        const int c  = t & 15;    // 4-point group
        const int dp = t >> 4;    // d pair 0..15
        for (int it = 0; it < 8; ++it) {
            const int d = it * 32 + dp * 2;
            float4 v0 = *reinterpret_cast<const float4*>(inb + (size_t)d * 1024 + c * 4);
            float4 v1 = *reinterpret_cast<const float4*>(inb + (size_t)(d + 1) * 1024 + c * 4);
            float a0[4] = {v0.x, v0.y, v0.z, v0.w};
            float a1[4] = {v1.x, v1.y, v1.z, v1.w};
#pragma unroll
            for (int j = 0; j < 4; ++j) {
                int p = 4 * c + j;
                f16 h0 = (f16)a0[j], h1 = (f16)a1[j];
                f16 l0 = (f16)(a0[j] - (float)h0), l1 = (f16)(a1[j] - (float)h1);
                int off = (p * 512 + d * 2) ^ ((p & 15) << 4);
                union { f16 h[2]; unsigned u; } ph, pl;
                ph.h[0] = h0; ph.h[1] = h1;
                pl.h[0] = l0; pl.h[1] = l1;
                *reinterpret_cast<unsigned*>(lds + off) = ph.u;
                *reinterpret_cast<unsigned*>(lds + 32768 + off) = pl.u;
            }
        }
    }
    __syncthreads();

    const int lane = t & 63, w = t >> 6;
    const int col = lane & 15, q = lane >> 4;
    const int kw0 = w * 256;
    const int cxor = col << 4;
    const int qoff = q << 4;          // q*16 bytes = 8 f16

    int xbase[4];
#pragma unroll
    for (int ct = 0; ct < 4; ++ct) xbase[ct] = (ct * 16 + col) * 512;

    float bd1[4], bd2[4];
    int   bi1[4], bi2[4];
#pragma unroll
    for (int ct = 0; ct < 4; ++ct) { bd1[ct] = 3.4e38f; bd2[ct] = 3.4e38f; bi1[ct] = 0; bi2[ct] = 0; }

#pragma unroll 1
    for (int ks = 0; ks < 16; ks += 2) {
        const int kbase = kw0 + ks * 16;
        f32x4 acc[2][4];
#pragma unroll
        for (int kj = 0; kj < 2; ++kj)
#pragma unroll
            for (int ct = 0; ct < 4; ++ct) acc[kj][ct] = (f32x4){0, 0, 0, 0};

        const size_t ebase0 = ((size_t)(kbase + col) << 8) + (q << 3);
        const size_t ebase1 = ((size_t)(kbase + 16 + col) << 8) + (q << 3);

#pragma unroll
        for (int ds = 0; ds < 8; ++ds) {
            f16x8 eh0 = *reinterpret_cast<const f16x8*>(ehs + ebase0 + ds * 32);
            f16x8 el0 = *reinterpret_cast<const f16x8*>(els + ebase0 + ds * 32);
            f16x8 eh1 = *reinterpret_cast<const f16x8*>(ehs + ebase1 + ds * 32);
            f16x8 el1 = *reinterpret_cast<const f16x8*>(els + ebase1 + ds * 32);
#pragma unroll
            for (int ct = 0; ct < 4; ++ct) {
                int xo = xbase[ct] + ((ds * 64 + qoff) ^ cxor);   // XOR on full d-offset
                f16x8 xh = *reinterpret_cast<const f16x8*>(lds + xo);
                f16x8 xl = *reinterpret_cast<const f16x8*>(lds + 32768 + xo);
                acc[0][ct] = __builtin_amdgcn_mfma_f32_16x16x32_f16(eh0, xh, acc[0][ct], 0, 0, 0);
                acc[0][ct] = __builtin_amdgcn_mfma_f32_16x16x32_f16(el0, xh, acc[0][ct], 0, 0, 0);
                acc[0][ct] = __builtin_amdgcn_mfma_f32_16x16x32_f16(eh0, xl, acc[0][ct], 0, 0, 0);
                acc[1][ct] = __builtin_amdgcn_mfma_f32_16x16x32_f16(eh1, xh, acc[1][ct], 0, 0, 0);
                acc[1][ct] = __builtin_amdgcn_mfma_f32_16x16x32_f16(el1, xh, acc[1][ct], 0, 0, 0);
                acc[1][ct] = __builtin_amdgcn_mfma_f32_16x16x32_f16(eh1, xl, acc[1][ct], 0, 0, 0);
            }
        }

#pragma unroll
        for (int kj = 0; kj < 2; ++kj) {
            const int kb = kbase + kj * 16;
            float4 env = *reinterpret_cast<const float4*>(enorm + kb + q * 4);
            float en4[4] = {env.x, env.y, env.z, env.w};
#pragma unroll
            for (int ct = 0; ct < 4; ++ct)
#pragma unroll
                for (int r = 0; r < 4; ++r) {
                    float s = en4[r] - 2.0f * acc[kj][ct][r];
                    int k = kb + q * 4 + r;
                    if (s < bd1[ct]) {
                        bd2[ct] = bd1[ct]; bi2[ct] = bi1[ct];
                        bd1[ct] = s;       bi1[ct] = k;
                    } else if (s < bd2[ct]) {
                        bd2[ct] = s; bi2[ct] = k;
                    }
                }
        }
    }

    // top-2 merge across the 4 q-groups (lanes sharing col); disjoint candidate sets
#pragma unroll
    for (int ct = 0; ct < 4; ++ct) {
#pragma unroll
        for (int m = 16; m <= 32; m <<= 1) {
            float ob1 = __shfl_xor(bd1[ct], m); int oi1 = __shfl_xor(bi1[ct], m);
            float ob2 = __shfl_xor(bd2[ct], m); int oi2 = __shfl_xor(bi2[ct], m);
            if (ob1 < bd1[ct] || (ob1 == bd1[ct] && oi1 < bi1[ct])) {
                float nb2; int ni2;
                if (bd1[ct] < ob2 || (bd1[ct] == ob2 && bi1[ct] < oi2)) { nb2 = bd1[ct]; ni2 = bi1[ct]; }
                else { nb2 = ob2; ni2 = oi2; }
                bd1[ct] = ob1; bi1[ct] = oi1; bd2[ct] = nb2; bi2[ct] = ni2;
            } else if (ob1 < bd2[ct] || (ob1 == bd2[ct] && oi1 < bi2[ct])) {
                bd2[ct] = ob1; bi2[ct] = oi1;
            }
        }
    }

    // merge the 4 waves' code-slices via LDS (reuse xs after barrier)
    __syncthreads();
    float* m1 = reinterpret_cast<float*>(lds);           // [4][64]
    int*   n1 = reinterpret_cast<int*>(lds + 1024);
    float* m2 = reinterpret_cast<float*>(lds + 2048);
    int*   n2 = reinterpret_cast<int*>(lds + 3072);
    if (q == 0) {
#pragma unroll
        for (int ct = 0; ct < 4; ++ct) {
            int s = w * 64 + ct * 16 + col;
            m1[s] = bd1[ct]; n1[s] = bi1[ct];
            m2[s] = bd2[ct]; n2[s] = bi2[ct];
        }
    }
    __syncthreads();
    if (t < 64) {
        float b1 = m1[t]; int i1 = n1[t];
        float b2 = m2[t]; int i2 = n2[t];
#pragma unroll
        for (int ww = 1; ww < 4; ++ww) {
            float ob1 = m1[ww * 64 + t]; int oi1 = n1[ww * 64 + t];
            float ob2 = m2[ww * 64 + t]; int oi2 = n2[ww * 64 + t];
            if (ob1 < b1 || (ob1 == b1 && oi1 < i1)) {
                float nb2; int ni2;
                if (b1 < ob2 || (b1 == ob2 && i1 < oi2)) { nb2 = b1; ni2 = i1; }
                else { nb2 = ob2; ni2 = oi2; }
                b1 = ob1; i1 = oi1; b2 = nb2; i2 = ni2;
            } else if (ob1 < b2 || (ob1 == b2 && oi1 < i2)) {
                b2 = ob1; i2 = oi1;
            }
        }
        i2a[n0 + t] = i1;
        i2b[n0 + t] = i2;
    }
}

// ---------------- K1b: exact fp32 re-score of the two candidates ----------------
__global__ __launch_bounds__(256) void refine_kernel(
    const float* __restrict__ in, const float* __restrict__ emb,
    const float* __restrict__ enorm, const int* __restrict__ i2a,
    const int* __restrict__ i2b, int* __restrict__ idx_out)
{
    __shared__ float red[2][4][64];
    const int t = threadIdx.x;
    const int p = t & 63, cq = t >> 6;
    const int n0 = blockIdx.x * 64;
    const int b = n0 >> 10, hw0 = n0 & 1023;
    const int k0 = i2a[n0 + p], k1 = i2b[n0 + p];
    const float* e0 = emb + (size_t)k0 * Dd + cq * 64;
    const float* e1 = emb + (size_t)k1 * Dd + cq * 64;
    const float* xb = in + (size_t)b * (Dd * 1024) + (size_t)(cq * 64) * 1024 + hw0 + p;
    float d0 = 0.f, d1 = 0.f;
    for (int c = 0; c < 64; c += 4) {
        float4 a0 = *reinterpret_cast<const float4*>(e0 + c);
        float4 a1 = *reinterpret_cast<const float4*>(e1 + c);
        float x0 = xb[(size_t)(c + 0) * 1024];
        float x1 = xb[(size_t)(c + 1) * 1024];
        float x2 = xb[(size_t)(c + 2) * 1024];
        float x3 = xb[(size_t)(c + 3) * 1024];
        d0 = fmaf(x3, a0.w, fmaf(x2, a0.z, fmaf(x1, a0.y, fmaf(x0, a0.x, d0))));
        d1 = fmaf(x3, a1.w, fmaf(x2, a1.z, fmaf(x1, a1.y, fmaf(x0, a1.x, d1))));
    }
    red[0][cq][p] = d0;
    red[1][cq][p] = d1;
    __syncthreads();
    if (t < 64) {
        float dot0 = (red[0][0][t] + red[0][1][t]) + (red[0][2][t] + red[0][3][t]);
        float dot1 = (red[1][0][t] + red[1][1][t]) + (red[1][2][t] + red[1][3][t]);
        float s0 = enorm[k0] - 2.f * dot0;
        float s1 = enorm[k1] - 2.f * dot1;
        idx_out[n0 + t] = (s1 < s0 || (s1 == s0 && k1 < k0)) ? k1 : k0;
    }
}

// ---------------- K2: quantized output + loss partials + counts ----------------
__global__ __launch_bounds__(256) void quant_kernel(
    const float* __restrict__ in, const float* __restrict__ emb,
    const int* __restrict__ idx, float* __restrict__ outq,
    float* __restrict__ partials, int* __restrict__ counts)
{
    __shared__ float sred[4];
    const int t  = threadIdx.x;
    const int p  = t & 63;
    const int cq = t >> 6;
    const int n0 = blockIdx.x * 64;
    const int b   = n0 >> 10;
    const int hw0 = n0 & 1023;
    const int row = idx[n0 + p];
    if (t < 64) atomicAdd(&counts[row], 1);

    const float* erow = emb + (size_t)row * Dd;
    const size_t base = (size_t)b * Dd * 1024 + hw0 + p;
    float ls = 0.f;
    for (int c0 = cq * 64; c0 < cq * 64 + 64; c0 += 4) {
        float4 ev = *reinterpret_cast<const float4*>(erow + c0);
        float e4[4] = {ev.x, ev.y, ev.z, ev.w};
#pragma unroll
        for (int j = 0; j < 4; ++j) {
            size_t a = base + (size_t)(c0 + j) * 1024;
            float qv = e4[j];
            float x = in[a];
            outq[a] = qv;
            float df = qv - x;
            ls = fmaf(df, df, ls);
        }
    }
#pragma unroll
    for (int m = 1; m < 64; m <<= 1) ls += __shfl_xor(ls, m);
    if ((t & 63) == 0) sred[t >> 6] = ls;
    __syncthreads();
    if (t == 0) partials[blockIdx.x] = (sred[0] + sred[1]) + (sred[2] + sred[3]);
}

// ---------------- K3: one-hot encodings (256 MB fill) ----------------
__global__ void enc_kernel(const int* __restrict__ idx, float* __restrict__ enc) {
    const long long T = 16777215LL;
    long long gid    = (long long)blockIdx.x * 256 + threadIdx.x;
    long long stride = (long long)gridDim.x * 256;
    if (gid == 0) {
        enc[0] = (idx[0] == 0) ? 1.f : 0.f;
        enc[1] = (idx[0] == 1) ? 1.f : 0.f;
        enc[67108862LL] = (idx[65535] == 1022) ? 1.f : 0.f;
        enc[67108863LL] = (idx[65535] == 1023) ? 1.f : 0.f;
    }
    for (long long c = gid; c < T; c += stride) {
        long long rel = 2 + 4 * c;
        int n  = (int)(rel >> 10);
        int kk = (int)(rel & 1023);
        float4 v;
        if (kk <= 1020) {
            int iv = idx[n];
            v.x = (kk     == iv) ? 1.f : 0.f;
            v.y = (kk + 1 == iv) ? 1.f : 0.f;
            v.z = (kk + 2 == iv) ? 1.f : 0.f;
            v.w = (kk + 3 == iv) ? 1.f : 0.f;
        } else {
            float o[4];
#pragma unroll
            for (int j = 0; j < 4; ++j) {
                long long rr = rel + j;
                int nn = (int)(rr >> 10);
                int kj = (int)(rr & 1023);
                o[j] = (idx[nn] == kj) ? 1.f : 0.f;
            }
            v.x = o[0]; v.y = o[1]; v.z = o[2]; v.w = o[3];
        }
        *reinterpret_cast<float4*>(enc + rel) = v;
    }
}

// ---------------- K4: finalize loss + perplexity ----------------
__global__ __launch_bounds__(1024) void fin_kernel(
    const int* __restrict__ counts, const float* __restrict__ partials,
    float* __restrict__ out)
{
    __shared__ float r1[16];
    __shared__ float r2[16];
    const int t = threadIdx.x;
    float pl = partials[t];
    float pv = (float)counts[t] * (1.0f / 65536.0f);
    float pp = pv * logf(pv + 1e-10f);
#pragma unroll
    for (int m = 1; m < 64; m <<= 1) {
        pl += __shfl_xor(pl, m);
        pp += __shfl_xor(pp, m);
    }
    if ((t & 63) == 0) { r1[t >> 6] = pl; r2[t >> 6] = pp; }
    __syncthreads();
    if (t == 0) {
        float s1 = 0.f, s2 = 0.f;
#pragma unroll
        for (int i = 0; i < 16; ++i) { s1 += r1[i]; s2 += r2[i]; }
        out[0]        = 0.25f * s1 / 16777216.0f;
        out[PERP_OFF] = expf(-s2);
    }
}

extern "C" void kernel_launch(void* const* d_in, const int* in_sizes, int n_in,
                              void* d_out, int out_size, void* d_ws, size_t ws_size,
                              hipStream_t stream) {
    const float* in  = (const float*)d_in[0];
    const float* emb = (const float*)d_in[1];
    float* out = (float*)d_out;

    char* ws = (char*)d_ws;
    int*   counts   = (int*)ws;                // 4 KB
    float* partials = (float*)(ws + 4096);     // 4 KB
    int*   idx      = (int*)(ws + 16384);      // 256 KB

    // Scratch carved from the tail of the 268 MB encodings output region;
    // all consumed before enc_kernel overwrites it.
    //   ehs: 262144 f16 (512 KB) | els: 262144 f16 (512 KB) | enorm: 1024 f32 (4 KB)
    //   i2a: 65536 int (256 KB)  | i2b: 65536 int (256 KB)   => 1,576,960 B total
    const size_t tailBytes = 524288 + 524288 + 4096 + 262144 + 262144;
    uintptr_t base = ((uintptr_t)(out + ENC_OFF + ENC_CNT) - tailBytes) & ~(uintptr_t)255;
    f16*   ehs   = (f16*)base;
    f16*   els   = (f16*)(base + 524288);
    float* enorm = (float*)(base + 1048576);
    int*   i2a   = (int*)(base + 1052672);
    int*   i2b   = (int*)(base + 1314816);

    hipMemsetAsync(counts, 0, 4096, stream);
    prep_kernel<<<256, 256, 0, stream>>>(emb, ehs, els, enorm);
    argmin_kernel<<<1024, 256, 0, stream>>>(in, ehs, els, enorm, i2a, i2b);
    refine_kernel<<<1024, 256, 0, stream>>>(in, emb, enorm, i2a, i2b, idx);
    quant_kernel<<<1024, 256, 0, stream>>>(in, emb, idx, out + QOFF, partials, counts);
    enc_kernel<<<8192, 256, 0, stream>>>(idx, out + ENC_OFF);
    fin_kernel<<<1, 1024, 0, stream>>>(counts, partials, out);
}

// Round 5
// 409.911 us; speedup vs baseline: 1.4156x; 1.0395x over previous
//
#include <hip/hip_runtime.h>

typedef _Float16 f16;
typedef _Float16 f16x4 __attribute__((ext_vector_type(4)));
typedef _Float16 f16x8 __attribute__((ext_vector_type(8)));
typedef float f32x4 __attribute__((ext_vector_type(4)));

constexpr int Dd = 256;
constexpr long long QOFF     = 1;
constexpr long long PERP_OFF = 16777217LL;
constexpr long long ENC_OFF  = 16777218LL;
constexpr long long ENC_CNT  = 67108864LL;

__device__ inline f32x4 ntload4(const float* p) {
    return __builtin_nontemporal_load(reinterpret_cast<const f32x4*>(p));
}

// ---------------- K0: split codebook to fp16 hi/lo + exact row norms ----------------
__global__ void prep_kernel(const float* __restrict__ emb, f16* __restrict__ ehs,
                            f16* __restrict__ els, float* __restrict__ enorm) {
    const int t = threadIdx.x;
    const int k = blockIdx.x * 4 + (t >> 6);
    const int d4 = (t & 63) * 4;
    float4 v = *reinterpret_cast<const float4*>(emb + (size_t)k * Dd + d4);
    float s = v.x * v.x + v.y * v.y + v.z * v.z + v.w * v.w;
#pragma unroll
    for (int m = 1; m < 64; m <<= 1) s += __shfl_xor(s, m);
    float a[4] = {v.x, v.y, v.z, v.w};
    f16x4 h, l;
#pragma unroll
    for (int j = 0; j < 4; ++j) {
        h[j] = (f16)a[j];
        l[j] = (f16)(a[j] - (float)h[j]);
    }
    *reinterpret_cast<f16x4*>(ehs + (size_t)k * Dd + d4) = h;
    *reinterpret_cast<f16x4*>(els + (size_t)k * Dd + d4) = l;
    if ((t & 63) == 0) enorm[k] = s;
}

// ---------------- K1: MFMA top-2 argmin (2-pass: (eh+el)·xh) ----------------
// Block 256 thr = 4 waves, 64 points. xh staged [p][d] fp16 in LDS, XOR-swizzled.
// Wave w handles codes [w*256, w*256+256), two 16-code chunks per x-fragment load.
__global__ __launch_bounds__(256, 4) void argmin_kernel(
    const float* __restrict__ in, const f16* __restrict__ ehs,
    const f16* __restrict__ els, const float* __restrict__ enorm,
    int* __restrict__ i2a, int* __restrict__ i2b)
{
    __shared__ char lds[32768];   // xh[64][256] f16, swizzled: off=(p*512+d*2)^((p&15)<<4)
    const int t  = threadIdx.x;
    const int n0 = blockIdx.x * 64;
    const int b = n0 >> 10, hw0 = n0 & 1023;
    const float* inb = in + (size_t)b * (Dd * 1024) + hw0;

    // ---- stage xh (nontemporal x loads; d-permute by c>>2 kills 4-way write conflicts)
    {
        const int c  = t & 15;            // 4-point group
        const int g  = (t >> 4) & 3;      // raw d sub-pair
        const int hi = t >> 6;            // wave -> d block 0..3
        const int dp = hi * 4 + (g ^ (c >> 2));
        for (int it = 0; it < 8; ++it) {
            const int d = it * 32 + dp * 2;
            f32x4 v0 = ntload4(inb + (size_t)d * 1024 + c * 4);
            f32x4 v1 = ntload4(inb + (size_t)(d + 1) * 1024 + c * 4);
#pragma unroll
            for (int j = 0; j < 4; ++j) {
                int p = 4 * c + j;
                f16 h0 = (f16)v0[j], h1 = (f16)v1[j];
                int off = (p * 512 + d * 2) ^ ((p & 15) << 4);
                union { f16 h[2]; unsigned u; } ph;
                ph.h[0] = h0; ph.h[1] = h1;
                *reinterpret_cast<unsigned*>(lds + off) = ph.u;
            }
        }
    }
    __syncthreads();

    const int lane = t & 63, w = t >> 6;
    const int col = lane & 15, q = lane >> 4;
    const int kw0 = w * 256;
    const int cxor = col << 4;
    const int qoff = q << 4;          // q*16 bytes = 8 f16

    int xbase[4];
#pragma unroll
    for (int ct = 0; ct < 4; ++ct) xbase[ct] = (ct * 16 + col) * 512;

    float bd1[4], bd2[4];
    int   bi1[4], bi2[4];
#pragma unroll
    for (int ct = 0; ct < 4; ++ct) { bd1[ct] = 3.4e38f; bd2[ct] = 3.4e38f; bi1[ct] = 0; bi2[ct] = 0; }

#pragma unroll 1
    for (int ks = 0; ks < 16; ks += 2) {
        const int kbase = kw0 + ks * 16;
        f32x4 acc[2][4];
#pragma unroll
        for (int kj = 0; kj < 2; ++kj)
#pragma unroll
            for (int ct = 0; ct < 4; ++ct) acc[kj][ct] = (f32x4){0, 0, 0, 0};

        const f16* pe0h = ehs + ((size_t)(kbase + col) << 8) + (q << 3);
        const f16* pe0l = els + ((size_t)(kbase + col) << 8) + (q << 3);
        const f16* pe1h = pe0h + (16 << 8);
        const f16* pe1l = pe0l + (16 << 8);

#pragma unroll
        for (int ds = 0; ds < 8; ++ds) {
            f16x8 h0 = *reinterpret_cast<const f16x8*>(pe0h + ds * 32);
            f16x8 l0 = *reinterpret_cast<const f16x8*>(pe0l + ds * 32);
            f16x8 h1 = *reinterpret_cast<const f16x8*>(pe1h + ds * 32);
            f16x8 l1 = *reinterpret_cast<const f16x8*>(pe1l + ds * 32);
#pragma unroll
            for (int ct = 0; ct < 4; ++ct) {
                int xo = xbase[ct] + ((ds * 64 + qoff) ^ cxor);
                f16x8 xh = *reinterpret_cast<const f16x8*>(lds + xo);
                acc[0][ct] = __builtin_amdgcn_mfma_f32_16x16x32_f16(h0, xh, acc[0][ct], 0, 0, 0);
                acc[0][ct] = __builtin_amdgcn_mfma_f32_16x16x32_f16(l0, xh, acc[0][ct], 0, 0, 0);
                acc[1][ct] = __builtin_amdgcn_mfma_f32_16x16x32_f16(h1, xh, acc[1][ct], 0, 0, 0);
                acc[1][ct] = __builtin_amdgcn_mfma_f32_16x16x32_f16(l1, xh, acc[1][ct], 0, 0, 0);
            }
        }

#pragma unroll
        for (int kj = 0; kj < 2; ++kj) {
            const int kb = kbase + kj * 16;
            float4 env = *reinterpret_cast<const float4*>(enorm + kb + q * 4);
            float en4[4] = {env.x, env.y, env.z, env.w};
#pragma unroll
            for (int ct = 0; ct < 4; ++ct)
#pragma unroll
                for (int r = 0; r < 4; ++r) {
                    float s = en4[r] - 2.0f * acc[kj][ct][r];
                    int k = kb + q * 4 + r;
                    if (s < bd1[ct]) {
                        bd2[ct] = bd1[ct]; bi2[ct] = bi1[ct];
                        bd1[ct] = s;       bi1[ct] = k;
                    } else if (s < bd2[ct]) {
                        bd2[ct] = s; bi2[ct] = k;
                    }
                }
        }
    }

    // top-2 merge across the 4 q-groups (lanes sharing col)
#pragma unroll
    for (int ct = 0; ct < 4; ++ct) {
#pragma unroll
        for (int m = 16; m <= 32; m <<= 1) {
            float ob1 = __shfl_xor(bd1[ct], m); int oi1 = __shfl_xor(bi1[ct], m);
            float ob2 = __shfl_xor(bd2[ct], m); int oi2 = __shfl_xor(bi2[ct], m);
            if (ob1 < bd1[ct] || (ob1 == bd1[ct] && oi1 < bi1[ct])) {
                float nb2; int ni2;
                if (bd1[ct] < ob2 || (bd1[ct] == ob2 && bi1[ct] < oi2)) { nb2 = bd1[ct]; ni2 = bi1[ct]; }
                else { nb2 = ob2; ni2 = oi2; }
                bd1[ct] = ob1; bi1[ct] = oi1; bd2[ct] = nb2; bi2[ct] = ni2;
            } else if (ob1 < bd2[ct] || (ob1 == bd2[ct] && oi1 < bi2[ct])) {
                bd2[ct] = ob1; bi2[ct] = oi1;
            }
        }
    }

    // merge the 4 waves' code-slices via LDS (reuse xh space after barrier)
    __syncthreads();
    float* m1 = reinterpret_cast<float*>(lds);           // [4][64]
    int*   n1 = reinterpret_cast<int*>(lds + 1024);
    float* m2 = reinterpret_cast<float*>(lds + 2048);
    int*   n2 = reinterpret_cast<int*>(lds + 3072);
    if (q == 0) {
#pragma unroll
        for (int ct = 0; ct < 4; ++ct) {
            int s = w * 64 + ct * 16 + col;
            m1[s] = bd1[ct]; n1[s] = bi1[ct];
            m2[s] = bd2[ct]; n2[s] = bi2[ct];
        }
    }
    __syncthreads();
    if (t < 64) {
        float b1 = m1[t]; int i1 = n1[t];
        float b2 = m2[t]; int i2 = n2[t];
#pragma unroll
        for (int ww = 1; ww < 4; ++ww) {
            float ob1 = m1[ww * 64 + t]; int oi1 = n1[ww * 64 + t];
            float ob2 = m2[ww * 64 + t]; int oi2 = n2[ww * 64 + t];
            if (ob1 < b1 || (ob1 == b1 && oi1 < i1)) {
                float nb2; int ni2;
                if (b1 < ob2 || (b1 == ob2 && i1 < oi2)) { nb2 = b1; ni2 = i1; }
                else { nb2 = ob2; ni2 = oi2; }
                b1 = ob1; i1 = oi1; b2 = nb2; i2 = ni2;
            } else if (ob1 < b2 || (ob1 == b2 && oi1 < i2)) {
                b2 = ob1; i2 = oi1;
            }
        }
        i2a[n0 + t] = i1;
        i2b[n0 + t] = i2;
    }
}

// ---------------- K2: fused exact refine + quantized + loss + counts + idx ----------------
__global__ __launch_bounds__(256) void quantref_kernel(
    const float* __restrict__ in, const float* __restrict__ emb,
    const float* __restrict__ enorm, const int* __restrict__ i2a,
    const int* __restrict__ i2b, int* __restrict__ idx_out,
    float* __restrict__ outq, float* __restrict__ partials, int* __restrict__ counts)
{
    __shared__ float red[2][4][64];
    __shared__ int rowsel[64];
    __shared__ float sred[4];
    const int t = threadIdx.x;
    const int p = t & 63, cq = t >> 6;
    const int n0 = blockIdx.x * 64;
    const int b = n0 >> 10, hw0 = n0 & 1023;
    const int k0 = i2a[n0 + p], k1 = i2b[n0 + p];
    const float* e0 = emb + (size_t)k0 * Dd + cq * 64;
    const float* e1 = emb + (size_t)k1 * Dd + cq * 64;
    const float* xb = in + (size_t)b * (Dd * 1024) + (size_t)(cq * 64) * 1024 + hw0 + p;

    float xr[64];
    float d0 = 0.f, d1 = 0.f;
#pragma unroll
    for (int c = 0; c < 64; c += 4) {
        float4 a0 = *reinterpret_cast<const float4*>(e0 + c);
        float4 a1 = *reinterpret_cast<const float4*>(e1 + c);
        xr[c + 0] = __builtin_nontemporal_load(xb + (size_t)(c + 0) * 1024);
        xr[c + 1] = __builtin_nontemporal_load(xb + (size_t)(c + 1) * 1024);
        xr[c + 2] = __builtin_nontemporal_load(xb + (size_t)(c + 2) * 1024);
        xr[c + 3] = __builtin_nontemporal_load(xb + (size_t)(c + 3) * 1024);
        d0 = fmaf(xr[c+3], a0.w, fmaf(xr[c+2], a0.z, fmaf(xr[c+1], a0.y, fmaf(xr[c+0], a0.x, d0))));
        d1 = fmaf(xr[c+3], a1.w, fmaf(xr[c+2], a1.z, fmaf(xr[c+1], a1.y, fmaf(xr[c+0], a1.x, d1))));
    }
    red[0][cq][p] = d0;
    red[1][cq][p] = d1;
    __syncthreads();
    if (t < 64) {
        float dot0 = (red[0][0][t] + red[0][1][t]) + (red[0][2][t] + red[0][3][t]);
        float dot1 = (red[1][0][t] + red[1][1][t]) + (red[1][2][t] + red[1][3][t]);
        float s0 = enorm[k0] - 2.f * dot0;
        float s1 = enorm[k1] - 2.f * dot1;
        int row = (s1 < s0 || (s1 == s0 && k1 < k0)) ? k1 : k0;
        rowsel[t] = row;
        idx_out[n0 + t] = row;
        atomicAdd(&counts[row], 1);
    }
    __syncthreads();

    const int row = rowsel[p];
    const float* erow = emb + (size_t)row * Dd + cq * 64;
    const size_t base = (size_t)b * (Dd * 1024) + (size_t)(cq * 64) * 1024 + hw0 + p;
    float ls = 0.f;
#pragma unroll
    for (int c = 0; c < 64; c += 4) {
        float4 ev = *reinterpret_cast<const float4*>(erow + c);
        float e4[4] = {ev.x, ev.y, ev.z, ev.w};
#pragma unroll
        for (int j = 0; j < 4; ++j) {
            size_t a = base + (size_t)(c + j) * 1024;
            __builtin_nontemporal_store(e4[j], outq + a);
            float df = e4[j] - xr[c + j];
            ls = fmaf(df, df, ls);
        }
    }
#pragma unroll
    for (int m = 1; m < 64; m <<= 1) ls += __shfl_xor(ls, m);
    if ((t & 63) == 0) sred[t >> 6] = ls;
    __syncthreads();
    if (t == 0) partials[blockIdx.x] = (sred[0] + sred[1]) + (sred[2] + sred[3]);
}

// ---------------- K3: one-hot encodings (256 MB fill) ----------------
__global__ void enc_kernel(const int* __restrict__ idx, float* __restrict__ enc) {
    const long long T = 16777215LL;
    long long gid    = (long long)blockIdx.x * 256 + threadIdx.x;
    long long stride = (long long)gridDim.x * 256;
    if (gid == 0) {
        enc[0] = (idx[0] == 0) ? 1.f : 0.f;
        enc[1] = (idx[0] == 1) ? 1.f : 0.f;
        enc[67108862LL] = (idx[65535] == 1022) ? 1.f : 0.f;
        enc[67108863LL] = (idx[65535] == 1023) ? 1.f : 0.f;
    }
    for (long long c = gid; c < T; c += stride) {
        long long rel = 2 + 4 * c;
        int n  = (int)(rel >> 10);
        int kk = (int)(rel & 1023);
        f32x4 v;
        if (kk <= 1020) {
            int iv = idx[n];
            v[0] = (kk     == iv) ? 1.f : 0.f;
            v[1] = (kk + 1 == iv) ? 1.f : 0.f;
            v[2] = (kk + 2 == iv) ? 1.f : 0.f;
            v[3] = (kk + 3 == iv) ? 1.f : 0.f;
        } else {
#pragma unroll
            for (int j = 0; j < 4; ++j) {
                long long rr = rel + j;
                int nn = (int)(rr >> 10);
                int kj = (int)(rr & 1023);
                v[j] = (idx[nn] == kj) ? 1.f : 0.f;
            }
        }
        __builtin_nontemporal_store(v, reinterpret_cast<f32x4*>(enc + rel));
    }
}

// ---------------- K4: finalize loss + perplexity ----------------
__global__ __launch_bounds__(1024) void fin_kernel(
    const int* __restrict__ counts, const float* __restrict__ partials,
    float* __restrict__ out)
{
    __shared__ float r1[16];
    __shared__ float r2[16];
    const int t = threadIdx.x;
    float pl = partials[t];
    float pv = (float)counts[t] * (1.0f / 65536.0f);
    float pp = pv * logf(pv + 1e-10f);
#pragma unroll
    for (int m = 1; m < 64; m <<= 1) {
        pl += __shfl_xor(pl, m);
        pp += __shfl_xor(pp, m);
    }
    if ((t & 63) == 0) { r1[t >> 6] = pl; r2[t >> 6] = pp; }
    __syncthreads();
    if (t == 0) {
        float s1 = 0.f, s2 = 0.f;
#pragma unroll
        for (int i = 0; i < 16; ++i) { s1 += r1[i]; s2 += r2[i]; }
        out[0]        = 0.25f * s1 / 16777216.0f;
        out[PERP_OFF] = expf(-s2);
    }
}

extern "C" void kernel_launch(void* const* d_in, const int* in_sizes, int n_in,
                              void* d_out, int out_size, void* d_ws, size_t ws_size,
                              hipStream_t stream) {
    const float* in  = (const float*)d_in[0];
    const float* emb = (const float*)d_in[1];
    float* out = (float*)d_out;

    char* ws = (char*)d_ws;
    int*   counts   = (int*)ws;                // 4 KB
    float* partials = (float*)(ws + 4096);     // 4 KB
    int*   idx      = (int*)(ws + 16384);      // 256 KB

    // Scratch carved from the tail of the 268 MB encodings output region;
    // all consumed before enc_kernel overwrites it.
    const size_t tailBytes = 524288 + 524288 + 4096 + 262144 + 262144;
    uintptr_t base = ((uintptr_t)(out + ENC_OFF + ENC_CNT) - tailBytes) & ~(uintptr_t)255;
    f16*   ehs   = (f16*)base;
    f16*   els   = (f16*)(base + 524288);
    float* enorm = (float*)(base + 1048576);
    int*   i2a   = (int*)(base + 1052672);
    int*   i2b   = (int*)(base + 1314816);

    (void)hipMemsetAsync(counts, 0, 4096, stream);
    prep_kernel<<<256, 256, 0, stream>>>(emb, ehs, els, enorm);
    argmin_kernel<<<1024, 256, 0, stream>>>(in, ehs, els, enorm, i2a, i2b);
    quantref_kernel<<<1024, 256, 0, stream>>>(in, emb, enorm, i2a, i2b, idx,
                                              out + QOFF, partials, counts);
    enc_kernel<<<8192, 256, 0, stream>>>(idx, out + ENC_OFF);
    fin_kernel<<<1, 1024, 0, stream>>>(counts, partials, out);
}

// Round 6
// 354.971 us; speedup vs baseline: 1.6347x; 1.1548x over previous
//
#include <hip/hip_runtime.h>

typedef _Float16 f16;
typedef _Float16 f16x4 __attribute__((ext_vector_type(4)));
typedef _Float16 f16x8 __attribute__((ext_vector_type(8)));
typedef float f32x4 __attribute__((ext_vector_type(4)));

constexpr int Dd = 256;
constexpr long long QOFF     = 1;
constexpr long long PERP_OFF = 16777217LL;
constexpr long long ENC_OFF  = 16777218LL;
constexpr long long ENC_CNT  = 67108864LL;

__device__ inline f32x4 ntload4(const float* p) {
    return __builtin_nontemporal_load(reinterpret_cast<const f32x4*>(p));
}

// ---------------- K0: split codebook to fp16 hi/lo + exact row norms ----------------
__global__ void prep_kernel(const float* __restrict__ emb, f16* __restrict__ ehs,
                            f16* __restrict__ els, float* __restrict__ enorm) {
    const int t = threadIdx.x;
    const int k = blockIdx.x * 4 + (t >> 6);
    const int d4 = (t & 63) * 4;
    float4 v = *reinterpret_cast<const float4*>(emb + (size_t)k * Dd + d4);
    float s = v.x * v.x + v.y * v.y + v.z * v.z + v.w * v.w;
#pragma unroll
    for (int m = 1; m < 64; m <<= 1) s += __shfl_xor(s, m);
    float a[4] = {v.x, v.y, v.z, v.w};
    f16x4 h, l;
#pragma unroll
    for (int j = 0; j < 4; ++j) {
        h[j] = (f16)a[j];
        l[j] = (f16)(a[j] - (float)h[j]);
    }
    *reinterpret_cast<f16x4*>(ehs + (size_t)k * Dd + d4) = h;
    *reinterpret_cast<f16x4*>(els + (size_t)k * Dd + d4) = l;
    if ((t & 63) == 0) enorm[k] = s;
}

// ---------------- K1: MFMA top-2 argmin, 256-point tile ----------------
// Block 512 thr = 8 waves = 2 point-groups(128 pts) x 4 code-slices(256 codes).
// xh staged [p][d] fp16 in 128 KB LDS, XOR-swizzled off=(p*512+d*2)^((p&15)<<4).
// Grid 256 = 1 block/CU: all blocks stream the codebook in phase -> L2 reuse.
__global__ __launch_bounds__(512, 1) void argmin_kernel(
    const float* __restrict__ in, const f16* __restrict__ ehs,
    const f16* __restrict__ els, const float* __restrict__ enorm,
    int* __restrict__ i2a, int* __restrict__ i2b)
{
    __shared__ char lds[131072];
    const int t  = threadIdx.x;
    const int n0 = blockIdx.x * 256;
    const int b = n0 >> 10, hw0 = n0 & 1023;
    const float* inb = in + (size_t)b * (Dd * 1024) + hw0;

    // ---- stage xh: 256 pts x 256 d (nt loads; dpe permute spreads write banks)
    {
        const int c   = t & 63;                 // 4-point group
        const int dp  = t >> 6;                 // 0..7
        const int dpe = dp ^ ((c >> 3) & 7);
        for (int it = 0; it < 16; ++it) {
            const int d = it * 16 + dpe * 2;
            f32x4 v0 = ntload4(inb + (size_t)d * 1024 + c * 4);
            f32x4 v1 = ntload4(inb + (size_t)(d + 1) * 1024 + c * 4);
#pragma unroll
            for (int j = 0; j < 4; ++j) {
                int p = 4 * c + j;
                union { f16 h[2]; unsigned u; } ph;
                ph.h[0] = (f16)v0[j]; ph.h[1] = (f16)v1[j];
                int off = (p * 512 + d * 2) ^ ((p & 15) << 4);
                *reinterpret_cast<unsigned*>(lds + off) = ph.u;
            }
        }
    }
    __syncthreads();

    const int lane = t & 63, w = t >> 6;
    const int g   = w >> 2;        // point group 0..1
    const int cw  = w & 3;         // code slice 0..3
    const int col = lane & 15, q = lane >> 4;
    const int kw0 = cw * 256;
    const int pb  = g * 128;
    const int cxor = col << 4;
    const int qoff = q << 4;

    int xbase[8];
#pragma unroll
    for (int ct = 0; ct < 8; ++ct) xbase[ct] = (pb + ct * 16 + col) * 512;

    float bd1[8], bd2[8];
    int   bi1[8], bi2[8];
#pragma unroll
    for (int ct = 0; ct < 8; ++ct) { bd1[ct] = 3.4e38f; bd2[ct] = 3.4e38f; bi1[ct] = 0; bi2[ct] = 0; }

#pragma unroll 1
    for (int ks = 0; ks < 16; ks += 2) {
        const int kbase = kw0 + ks * 16;
        f32x4 acc[2][8];
#pragma unroll
        for (int kj = 0; kj < 2; ++kj)
#pragma unroll
            for (int ct = 0; ct < 8; ++ct) acc[kj][ct] = (f32x4){0, 0, 0, 0};

        const f16* pe0h = ehs + ((size_t)(kbase + col) << 8) + (q << 3);
        const f16* pe0l = els + ((size_t)(kbase + col) << 8) + (q << 3);
        const f16* pe1h = pe0h + (16 << 8);
        const f16* pe1l = pe0l + (16 << 8);

#pragma unroll
        for (int ds = 0; ds < 8; ++ds) {
            f16x8 h0 = *reinterpret_cast<const f16x8*>(pe0h + ds * 32);
            f16x8 l0 = *reinterpret_cast<const f16x8*>(pe0l + ds * 32);
            f16x8 h1 = *reinterpret_cast<const f16x8*>(pe1h + ds * 32);
            f16x8 l1 = *reinterpret_cast<const f16x8*>(pe1l + ds * 32);
#pragma unroll
            for (int ct = 0; ct < 8; ++ct) {
                int xo = xbase[ct] + ((ds * 64 + qoff) ^ cxor);
                f16x8 xh = *reinterpret_cast<const f16x8*>(lds + xo);
                acc[0][ct] = __builtin_amdgcn_mfma_f32_16x16x32_f16(h0, xh, acc[0][ct], 0, 0, 0);
                acc[0][ct] = __builtin_amdgcn_mfma_f32_16x16x32_f16(l0, xh, acc[0][ct], 0, 0, 0);
                acc[1][ct] = __builtin_amdgcn_mfma_f32_16x16x32_f16(h1, xh, acc[1][ct], 0, 0, 0);
                acc[1][ct] = __builtin_amdgcn_mfma_f32_16x16x32_f16(l1, xh, acc[1][ct], 0, 0, 0);
            }
        }

#pragma unroll
        for (int kj = 0; kj < 2; ++kj) {
            const int kb = kbase + kj * 16;
            float4 env = *reinterpret_cast<const float4*>(enorm + kb + q * 4);
            float en4[4] = {env.x, env.y, env.z, env.w};
#pragma unroll
            for (int ct = 0; ct < 8; ++ct)
#pragma unroll
                for (int r = 0; r < 4; ++r) {
                    float s = en4[r] - 2.0f * acc[kj][ct][r];
                    int k = kb + q * 4 + r;
                    if (s < bd1[ct]) {
                        bd2[ct] = bd1[ct]; bi2[ct] = bi1[ct];
                        bd1[ct] = s;       bi1[ct] = k;
                    } else if (s < bd2[ct]) {
                        bd2[ct] = s; bi2[ct] = k;
                    }
                }
        }
    }

    // top-2 merge across the 4 q-groups (lanes sharing col)
#pragma unroll
    for (int ct = 0; ct < 8; ++ct) {
#pragma unroll
        for (int m = 16; m <= 32; m <<= 1) {
            float ob1 = __shfl_xor(bd1[ct], m); int oi1 = __shfl_xor(bi1[ct], m);
            float ob2 = __shfl_xor(bd2[ct], m); int oi2 = __shfl_xor(bi2[ct], m);
            if (ob1 < bd1[ct] || (ob1 == bd1[ct] && oi1 < bi1[ct])) {
                float nb2; int ni2;
                if (bd1[ct] < ob2 || (bd1[ct] == ob2 && bi1[ct] < oi2)) { nb2 = bd1[ct]; ni2 = bi1[ct]; }
                else { nb2 = ob2; ni2 = oi2; }
                bd1[ct] = ob1; bi1[ct] = oi1; bd2[ct] = nb2; bi2[ct] = ni2;
            } else if (ob1 < bd2[ct] || (ob1 == bd2[ct] && oi1 < bi2[ct])) {
                bd2[ct] = ob1; bi2[ct] = oi1;
            }
        }
    }

    // merge the 4 code-slice waves per point-group via LDS (reuse xh space)
    __syncthreads();
    float* m1 = reinterpret_cast<float*>(lds);            // [8][128]
    int*   n1 = reinterpret_cast<int*>(lds + 4096);
    float* m2 = reinterpret_cast<float*>(lds + 8192);
    int*   n2 = reinterpret_cast<int*>(lds + 12288);
    if (q == 0) {
#pragma unroll
        for (int ct = 0; ct < 8; ++ct) {
            int s = w * 128 + ct * 16 + col;
            m1[s] = bd1[ct]; n1[s] = bi1[ct];
            m2[s] = bd2[ct]; n2[s] = bi2[ct];
        }
    }
    __syncthreads();
    if (t < 256) {
        const int p = t;
        const int g2 = p >> 7, lp = p & 127;
        const int wb = g2 * 4;
        float b1 = m1[wb * 128 + lp]; int i1 = n1[wb * 128 + lp];
        float b2 = m2[wb * 128 + lp]; int i2 = n2[wb * 128 + lp];
#pragma unroll
        for (int c2 = 1; c2 < 4; ++c2) {
            int s = (wb + c2) * 128 + lp;
            float ob1 = m1[s]; int oi1 = n1[s];
            float ob2 = m2[s]; int oi2 = n2[s];
            if (ob1 < b1 || (ob1 == b1 && oi1 < i1)) {
                float nb2; int ni2;
                if (b1 < ob2 || (b1 == ob2 && i1 < oi2)) { nb2 = b1; ni2 = i1; }
                else { nb2 = ob2; ni2 = oi2; }
                b1 = ob1; i1 = oi1; b2 = nb2; i2 = ni2;
            } else if (ob1 < b2 || (ob1 == b2 && oi1 < i2)) {
                b2 = ob1; i2 = oi1;
            }
        }
        i2a[n0 + p] = i1;
        i2b[n0 + p] = i2;
    }
}

// ---------------- K2: fused exact refine + quantized + loss + counts + idx ----------------
__global__ __launch_bounds__(256) void quantref_kernel(
    const float* __restrict__ in, const float* __restrict__ emb,
    const float* __restrict__ enorm, const int* __restrict__ i2a,
    const int* __restrict__ i2b, int* __restrict__ idx_out,
    float* __restrict__ outq, float* __restrict__ partials, int* __restrict__ counts)
{
    __shared__ float red[2][4][64];
    __shared__ int rowsel[64];
    __shared__ float sred[4];
    const int t = threadIdx.x;
    const int p = t & 63, cq = t >> 6;
    const int n0 = blockIdx.x * 64;
    const int b = n0 >> 10, hw0 = n0 & 1023;
    const int k0 = i2a[n0 + p], k1 = i2b[n0 + p];
    const float* e0 = emb + (size_t)k0 * Dd + cq * 64;
    const float* e1 = emb + (size_t)k1 * Dd + cq * 64;
    const float* xb = in + (size_t)b * (Dd * 1024) + (size_t)(cq * 64) * 1024 + hw0 + p;

    float xr[64];
    float d0 = 0.f, d1 = 0.f;
#pragma unroll
    for (int c = 0; c < 64; c += 4) {
        float4 a0 = *reinterpret_cast<const float4*>(e0 + c);
        float4 a1 = *reinterpret_cast<const float4*>(e1 + c);
        xr[c + 0] = __builtin_nontemporal_load(xb + (size_t)(c + 0) * 1024);
        xr[c + 1] = __builtin_nontemporal_load(xb + (size_t)(c + 1) * 1024);
        xr[c + 2] = __builtin_nontemporal_load(xb + (size_t)(c + 2) * 1024);
        xr[c + 3] = __builtin_nontemporal_load(xb + (size_t)(c + 3) * 1024);
        d0 = fmaf(xr[c+3], a0.w, fmaf(xr[c+2], a0.z, fmaf(xr[c+1], a0.y, fmaf(xr[c+0], a0.x, d0))));
        d1 = fmaf(xr[c+3], a1.w, fmaf(xr[c+2], a1.z, fmaf(xr[c+1], a1.y, fmaf(xr[c+0], a1.x, d1))));
    }
    red[0][cq][p] = d0;
    red[1][cq][p] = d1;
    __syncthreads();
    if (t < 64) {
        float dot0 = (red[0][0][t] + red[0][1][t]) + (red[0][2][t] + red[0][3][t]);
        float dot1 = (red[1][0][t] + red[1][1][t]) + (red[1][2][t] + red[1][3][t]);
        float s0 = enorm[k0] - 2.f * dot0;
        float s1 = enorm[k1] - 2.f * dot1;
        int row = (s1 < s0 || (s1 == s0 && k1 < k0)) ? k1 : k0;
        rowsel[t] = row;
        idx_out[n0 + t] = row;
        atomicAdd(&counts[row], 1);
    }
    __syncthreads();

    const int row = rowsel[p];
    const float* erow = emb + (size_t)row * Dd + cq * 64;
    const size_t base = (size_t)b * (Dd * 1024) + (size_t)(cq * 64) * 1024 + hw0 + p;
    float ls = 0.f;
#pragma unroll
    for (int c = 0; c < 64; c += 4) {
        float4 ev = *reinterpret_cast<const float4*>(erow + c);
        float e4[4] = {ev.x, ev.y, ev.z, ev.w};
#pragma unroll
        for (int j = 0; j < 4; ++j) {
            size_t a = base + (size_t)(c + j) * 1024;
            __builtin_nontemporal_store(e4[j], outq + a);
            float df = e4[j] - xr[c + j];
            ls = fmaf(df, df, ls);
        }
    }
#pragma unroll
    for (int m = 1; m < 64; m <<= 1) ls += __shfl_xor(ls, m);
    if ((t & 63) == 0) sred[t >> 6] = ls;
    __syncthreads();
    if (t == 0) partials[blockIdx.x] = (sred[0] + sred[1]) + (sred[2] + sred[3]);
}

// ---------------- K3: one-hot encodings (256 MB fill) ----------------
__global__ void enc_kernel(const int* __restrict__ idx, float* __restrict__ enc) {
    const long long T = 16777215LL;
    long long gid    = (long long)blockIdx.x * 256 + threadIdx.x;
    long long stride = (long long)gridDim.x * 256;
    if (gid == 0) {
        enc[0] = (idx[0] == 0) ? 1.f : 0.f;
        enc[1] = (idx[0] == 1) ? 1.f : 0.f;
        enc[67108862LL] = (idx[65535] == 1022) ? 1.f : 0.f;
        enc[67108863LL] = (idx[65535] == 1023) ? 1.f : 0.f;
    }
    for (long long c = gid; c < T; c += stride) {
        long long rel = 2 + 4 * c;
        int n  = (int)(rel >> 10);
        int kk = (int)(rel & 1023);
        f32x4 v;
        if (kk <= 1020) {
            int iv = idx[n];
            v[0] = (kk     == iv) ? 1.f : 0.f;
            v[1] = (kk + 1 == iv) ? 1.f : 0.f;
            v[2] = (kk + 2 == iv) ? 1.f : 0.f;
            v[3] = (kk + 3 == iv) ? 1.f : 0.f;
        } else {
#pragma unroll
            for (int j = 0; j < 4; ++j) {
                long long rr = rel + j;
                int nn = (int)(rr >> 10);
                int kj = (int)(rr & 1023);
                v[j] = (idx[nn] == kj) ? 1.f : 0.f;
            }
        }
        __builtin_nontemporal_store(v, reinterpret_cast<f32x4*>(enc + rel));
    }
}

// ---------------- K4: finalize loss + perplexity ----------------
__global__ __launch_bounds__(1024) void fin_kernel(
    const int* __restrict__ counts, const float* __restrict__ partials,
    float* __restrict__ out)
{
    __shared__ float r1[16];
    __shared__ float r2[16];
    const int t = threadIdx.x;
    float pl = partials[t];
    float pv = (float)counts[t] * (1.0f / 65536.0f);
    float pp = pv * logf(pv + 1e-10f);
#pragma unroll
    for (int m = 1; m < 64; m <<= 1) {
        pl += __shfl_xor(pl, m);
        pp += __shfl_xor(pp, m);
    }
    if ((t & 63) == 0) { r1[t >> 6] = pl; r2[t >> 6] = pp; }
    __syncthreads();
    if (t == 0) {
        float s1 = 0.f, s2 = 0.f;
#pragma unroll
        for (int i = 0; i < 16; ++i) { s1 += r1[i]; s2 += r2[i]; }
        out[0]        = 0.25f * s1 / 16777216.0f;
        out[PERP_OFF] = expf(-s2);
    }
}

extern "C" void kernel_launch(void* const* d_in, const int* in_sizes, int n_in,
                              void* d_out, int out_size, void* d_ws, size_t ws_size,
                              hipStream_t stream) {
    const float* in  = (const float*)d_in[0];
    const float* emb = (const float*)d_in[1];
    float* out = (float*)d_out;

    char* ws = (char*)d_ws;
    int*   counts   = (int*)ws;                // 4 KB
    float* partials = (float*)(ws + 4096);     // 4 KB
    int*   idx      = (int*)(ws + 16384);      // 256 KB

    // Scratch carved from the tail of the 268 MB encodings output region;
    // all consumed before enc_kernel overwrites it.
    const size_t tailBytes = 524288 + 524288 + 4096 + 262144 + 262144;
    uintptr_t base = ((uintptr_t)(out + ENC_OFF + ENC_CNT) - tailBytes) & ~(uintptr_t)255;
    f16*   ehs   = (f16*)base;
    f16*   els   = (f16*)(base + 524288);
    float* enorm = (float*)(base + 1048576);
    int*   i2a   = (int*)(base + 1052672);
    int*   i2b   = (int*)(base + 1314816);

    (void)hipMemsetAsync(counts, 0, 4096, stream);
    prep_kernel<<<256, 256, 0, stream>>>(emb, ehs, els, enorm);
    argmin_kernel<<<256, 512, 0, stream>>>(in, ehs, els, enorm, i2a, i2b);
    quantref_kernel<<<1024, 256, 0, stream>>>(in, emb, enorm, i2a, i2b, idx,
                                              out + QOFF, partials, counts);
    enc_kernel<<<8192, 256, 0, stream>>>(idx, out + ENC_OFF);
    fin_kernel<<<1, 1024, 0, stream>>>(counts, partials, out);
}